// Round 15
// baseline (196.780 us; speedup 1.0000x reference)
//
#include <hip/hip_runtime.h>
#include <hip/hip_bf16.h>

typedef __attribute__((ext_vector_type(8))) short short8;
typedef __attribute__((ext_vector_type(4))) float f32x4;
typedef __attribute__((ext_vector_type(16))) float f32x16;

#define B_ 8
#define C_ 64
#define H_ 256
#define W_ 256
#define HW_ 65536
#define K_ 10
#define NS1 24
#define NS2 18
#define HP_ 258
#define WP_ 258
#define PXP_ (HP_*WP_)
#define SLABW 34
#define SLABR 6

static __device__ __forceinline__ unsigned short f2bf(float f) {
    __hip_bfloat16 hb = __float2bfloat16(f);
    return *(unsigned short*)&hb;
}
static __device__ __forceinline__ float bf2f(unsigned short u) {
    unsigned v = ((unsigned)u) << 16;
    float f;
    __builtin_memcpy(&f, &v, 4);
    return f;
}

// async global->LDS 16B (dest = wave-uniform base + lane*16, linear in tau)
static __device__ __forceinline__ void gload_lds16(const void* g, void* l) {
    __builtin_amdgcn_global_load_lds(
        (const __attribute__((address_space(1))) unsigned int*)(unsigned long long)g,
        (__attribute__((address_space(3))) unsigned int*)(unsigned int)(unsigned long long)l,
        16, 0, 0);
}

// ---------------------------------------------------------------------------
// Fragment-ordered (32x32x16 layout), gamma-folded, expert-mixed weights.
// W4: [b][s(K32 step)][h2][of(2)][64 lane][8] bf16
//   o = of*32 + (l&31);  c = (s&1)*32 + h2*16 + (l>>5)*8 + j
//   s 0..17: conv taps (t = s>>1); s 18..23 (stage1): 1x1 experts m=(s-18)>>1.
// ---------------------------------------------------------------------------
__global__ void k_combine(const float* __restrict__ attn, const float* __restrict__ gamma,
                          const float* __restrict__ w1, const float* __restrict__ b1,
                          const float* __restrict__ w2, const float* __restrict__ b2,
                          const float* __restrict__ w16, const float* __restrict__ w168,
                          const float* __restrict__ w88,
                          unsigned short* __restrict__ W4_1, unsigned short* __restrict__ W4_2,
                          float* __restrict__ bias1, float* __restrict__ bias2) {
    const int N1 = B_ * NS1 * 2048;
    const int N2 = B_ * NS2 * 2048;
    int gid = blockIdx.x * 256 + threadIdx.x;
    if (gid < N1) {
        int b = gid / (NS1 * 2048);
        int r = gid - b * (NS1 * 2048);
        int s = r >> 11;
        int r2 = r & 2047;
        int h2 = (r2 >> 10) & 1;
        int of = (r2 >> 9) & 1;
        int l = (r2 >> 3) & 63, j = r2 & 7;
        int o = of * 32 + (l & 31);
        int c = (s & 1) * 32 + h2 * 16 + (l >> 5) * 8 + j;
        float val;
        if (s < 18) {
            int t = s >> 1;
            float acc = 0.f;
            #pragma unroll
            for (int k = 0; k < K_; ++k)
                acc += attn[b * K_ + k] * w2[((size_t)(k * 64 + o) * 64 + c) * 9 + t];
            val = acc * gamma[b * 64 + o];
        } else {
            int m = (s - 18) >> 1;
            const float* wm = (m == 0) ? w16 : (m == 1 ? w168 : w88);
            val = wm[o * 64 + c];
        }
        W4_1[gid] = f2bf(val);
    } else if (gid < N1 + N2) {
        int gid2 = gid - N1;
        int b = gid2 / (NS2 * 2048);
        int r = gid2 - b * (NS2 * 2048);
        int s = r >> 11;
        int r2 = r & 2047;
        int h2 = (r2 >> 10) & 1;
        int of = (r2 >> 9) & 1;
        int l = (r2 >> 3) & 63, j = r2 & 7;
        int o = of * 32 + (l & 31);
        int c = (s & 1) * 32 + h2 * 16 + (l >> 5) * 8 + j;
        int t = s >> 1;
        float acc = 0.f;
        #pragma unroll
        for (int k = 0; k < K_; ++k)
            acc += attn[b * K_ + k] * w1[((size_t)(k * 64 + o) * 64 + c) * 9 + t];
        W4_2[gid2] = f2bf(acc * gamma[b * 64 + o]);
    } else if (gid < N1 + N2 + 1024) {
        int id2 = gid - N1 - N2;
        int b = id2 >> 7;
        int rest = id2 & 127;
        int o = rest >> 1;
        int which = rest & 1;
        const float* bb = which ? b1 : b2;
        float acc = 0.f;
        #pragma unroll
        for (int k = 0; k < K_; ++k) acc += attn[b * K_ + k] * bb[k * 64 + o];
        float v = acc * gamma[b * 64 + o];
        if (which) bias2[b * 64 + o] = v; else bias1[b * 64 + o] = v;
    }
}

// ---------------------------------------------------------------------------
// Zero halo borders of the padded X1p / Tp buffers.
// ---------------------------------------------------------------------------
__global__ void k_border(unsigned short* __restrict__ X1p, unsigned short* __restrict__ Tp) {
    int gid = blockIdx.x * 256 + threadIdx.x;
    if (gid >= 2 * B_ * 1028 * 8) return;
    int chunk = gid & 7;
    int rest = gid >> 3;
    int p = rest % 1028;
    int rb = rest / 1028;
    int buf = rb & 1, b = rb >> 1;
    int row, col;
    if (p < 258) { row = 0; col = p; }
    else if (p < 516) { row = 257; col = p - 258; }
    else if (p < 772) { row = p - 516 + 1; col = 0; }
    else { row = p - 772 + 1; col = 257; }
    unsigned short* base = (buf ? Tp : X1p) +
        ((size_t)b * PXP_ + (size_t)row * WP_ + col) * 64 + chunk * 8;
    *(short8*)base = (short8){0, 0, 0, 0, 0, 0, 0, 0};
}

// ---------------------------------------------------------------------------
// x [b][64][HW] f32  ->  X1p [b][258][258][64] bf16 (interior only)
// ---------------------------------------------------------------------------
__global__ __launch_bounds__(256) void k_prep(const float* __restrict__ x,
                                              unsigned short* __restrict__ X1p) {
    __shared__ float ls[64][65];
    const int b = blockIdx.y;
    const int px0 = blockIdx.x * 64;
    const int row = px0 >> 8;
    const int col0 = px0 & 255;
    const int t = threadIdx.x;
    for (int e = t; e < 4096; e += 256) {
        int ch = e >> 6, px = e & 63;
        ls[ch][px] = x[((size_t)b * 64 + ch) * HW_ + px0 + px];
    }
    __syncthreads();
    unsigned short* dst = X1p + ((size_t)b * PXP_ + (size_t)(row + 1) * WP_ + col0 + 1) * 64;
    for (int e = t; e < 4096; e += 256) {
        int ch = e & 63, px = e >> 6;
        dst[(size_t)px * 64 + ch] = f2bf(ls[ch][px]);
    }
}

// ---------------------------------------------------------------------------
// Implicit-GEMM conv3x3 via MFMA 32x32x16 (R13 skeleton, bigger MFMA shape).
// Block: 128 thr / 2 waves; wave owns M=64 px (2 rows x 32 px), N=64 o.
// Per K32 step per wave: 4 A + 4 B ds_read_b128 (was 12 with 16x16) and
// 8 x mfma_f32_32x32x16_bf16 -> 33% fewer LDS bytes per FLOP (LDS pipe is
// the measured binding resource). 4 independent blocks/CU, 2 waves/SIMD.
// A: slab [6][34][64] via global_load_lds. B: 3-slot x 4KB ring, distance 2,
// counted vmcnt (never drain-0 mid-loop), raw s_barrier.
// ---------------------------------------------------------------------------
template<int STAGE>
__global__ __launch_bounds__(128, 2) void k_conv(
    const unsigned short* __restrict__ Xp,    // A source [b][258][258][64] bf16 padded
    const unsigned short* __restrict__ Xres,  // stage2 residual (X1p, bf16 padded)
    const float* __restrict__ par,            // stage1 [b][3][HW]
    const unsigned short* __restrict__ W4,    // [b][NS][2][2][64][8] bf16
    const float* __restrict__ bias,           // [b][64]
    unsigned short* __restrict__ Tp,          // stage1 out [b][258][258][64] bf16
    float* __restrict__ Fout)                 // stage2 out [b][64][HW] f32
{
    constexpr int NS = (STAGE == 1) ? NS1 : NS2;
    __shared__ short xs[SLABR * SLABW * 64];  // 26112 B (aliased as tl in epilogue)
    __shared__ short bring[3 * 2048];         // 12288 B B-ring (3 slots x 4KB)

    const int tid = threadIdx.x;
    const int l = tid & 63;
    const int wv = tid >> 6;                  // 0..1; wave owns rows 2wv, 2wv+1
    const int b = blockIdx.y;
    // XCD-aware bijective swizzle (512 blocks = 8 XCD x 64)
    const int bswz = (blockIdx.x & 7) * 64 + (blockIdx.x >> 3);
    const int rblk = bswz >> 3;               // 0..63
    const int cblk = bswz & 7;                // 0..7
    const int gh0 = rblk * 4, w0 = cblk * 32;
    const int ln31 = l & 31, g2 = l >> 5;

    const char* XbP = (const char*)Xp + (size_t)b * PXP_ * 128;
    const unsigned short* Wb = W4 + (size_t)b * (NS * 2048);

    // per-lane par values (stage1): A-frag mf -> img row gh0+2wv+mf, px w0+ln31
    float pvv[3][2];
    if constexpr (STAGE == 1) {
        #pragma unroll
        for (int m = 0; m < 3; ++m)
            #pragma unroll
            for (int mf = 0; mf < 2; ++mf)
                pvv[m][mf] = par[((size_t)b * 3 + m) * HW_ +
                                 (gh0 + 2 * wv + mf) * W_ + w0 + ln31];
    }

    f32x16 acc[2][2];
    #pragma unroll
    for (int mf = 0; mf < 2; ++mf)
        #pragma unroll
        for (int nf = 0; nf < 2; ++nf)
            #pragma unroll
            for (int q = 0; q < 16; ++q)
                acc[mf][nf][q] = 0.f;

    // ---- async-stage slab [6 rows][34 px][8 chunks]; swizzled src, linear dest
    #pragma unroll
    for (int it = 0; it < 13; ++it) {
        int tau = tid + it * 128;
        if (tau < SLABR * SLABW * 8) {
            int slot = tau & 7;
            int rest = tau >> 3;
            int px = rest % SLABW;
            int row = rest / SLABW;
            int cb = slot ^ (px & 7);
            gload_lds16(XbP + ((size_t)(gh0 + row) * WP_ + (w0 + px)) * 128 + cb * 16,
                        (char*)xs + (size_t)tau * 16);
        }
    }
    // ---- B stage: 4KB/step, 2 gloads per thread (128 thr), wave-uniform
    auto stage_b = [&](int s) {
        const char* src = (const char*)Wb + (size_t)s * 4096;
        char* dst = (char*)bring + (s % 3) * 4096;
        gload_lds16(src + tid * 16, dst + tid * 16);
        gload_lds16(src + 2048 + tid * 16, dst + 2048 + tid * 16);
    };
    stage_b(0);
    stage_b(1);

    // A-frag loader for 32x32x16: frag (h2, mf): row = 2wv+mf+dh,
    // px = ln31+dw, chunk c8 = (s&1)*4 + h2*2 + g2 (8-ch chunks)
    auto aload = [&](int s, short8 d[2][2]) {
        int dh, dw;
        if (STAGE == 1 && s >= 18) { dh = 1; dw = 1; }
        else { const int t = s >> 1; dh = t / 3; dw = t - 3 * dh; }
        const int h = s & 1;
        #pragma unroll
        for (int h2 = 0; h2 < 2; ++h2)
            #pragma unroll
            for (int mf = 0; mf < 2; ++mf) {
                int idx = ln31 + dw;
                int row = 2 * wv + mf + dh;
                int c8 = h * 4 + h2 * 2 + g2;
                d[h2][mf] = *(const short8*)((const char*)xs +
                             (row * SLABW + idx) * 128 + ((c8 ^ (idx & 7)) << 4));
            }
    };

    // prologue: slab + B0 landed; B1 (last 2 gloads) may float
    asm volatile("s_waitcnt vmcnt(2)" ::: "memory");
    __builtin_amdgcn_s_barrier();

    #pragma unroll
    for (int s = 0; s < NS; ++s) {
        // stage step s+2 into slot (s+2)%3 == (s-1)%3 (freed at last barrier)
        if (s + 2 < NS) stage_b(s + 2);
        // B frags from ring slot s%3: [h2][of] at h2*2048 + of*1024 bytes
        const char* rb = (const char*)bring + (s % 3) * 4096 + (size_t)l * 16;
        short8 bf[2][2];
        #pragma unroll
        for (int h2 = 0; h2 < 2; ++h2)
            #pragma unroll
            for (int of = 0; of < 2; ++of)
                bf[h2][of] = *(const short8*)(rb + h2 * 2048 + of * 1024);
        short8 a[2][2];
        aload(s, a);
        if (STAGE == 1 && s >= 18) {   // par-scaled 1x1 expert steps
            const int m = (s - 18) >> 1;
            #pragma unroll
            for (int h2 = 0; h2 < 2; ++h2)
                #pragma unroll
                for (int mf = 0; mf < 2; ++mf)
                    #pragma unroll
                    for (int j = 0; j < 8; ++j)
                        a[h2][mf][j] = (short)f2bf(bf2f((unsigned short)a[h2][mf][j]) * pvv[m][mf]);
        }
        __builtin_amdgcn_s_setprio(1);
        #pragma unroll
        for (int h2 = 0; h2 < 2; ++h2)
            #pragma unroll
            for (int mf = 0; mf < 2; ++mf)
                #pragma unroll
                for (int nf = 0; nf < 2; ++nf)
                    acc[mf][nf] = __builtin_amdgcn_mfma_f32_32x32x16_bf16(
                        a[h2][mf], bf[h2][nf], acc[mf][nf], 0, 0, 0);
        __builtin_amdgcn_s_setprio(0);
        if (s + 1 < NS) {
            // fence: stage(s+1) landed for ALL waves after the barrier;
            // own stage(s+2) (2 gloads) stays in flight - never drain-0 mid-loop
            if (s + 2 < NS) asm volatile("s_waitcnt vmcnt(2)" ::: "memory");
            else            asm volatile("s_waitcnt vmcnt(0)" ::: "memory");
            __builtin_amdgcn_s_barrier();
        }
    }

    // C/D map (32x32): col o = nf*32 + ln31; px = 4*g2 + (reg&3) + 8*(reg>>2)
    if constexpr (STAGE == 1) {
        // ---- epilogue: assemble 128B lines in slab-aliased LDS, store dwordx4
        __syncthreads();                       // all slab/ring reads done
        unsigned short* tl = (unsigned short*)xs;   // [4 rows][32 px][64 o^swz] = 16 KB
        #pragma unroll
        for (int nf = 0; nf < 2; ++nf) {
            int o = nf * 32 + ln31;
            float bi = bias[b * 64 + o];
            #pragma unroll
            for (int mf = 0; mf < 2; ++mf) {
                int row_local = 2 * wv + mf;
                #pragma unroll
                for (int reg = 0; reg < 16; ++reg) {
                    int px = 4 * g2 + (reg & 3) + 8 * (reg >> 2);
                    float v = fmaxf(acc[mf][nf][reg] + bi, 0.f);
                    tl[row_local * 2048 + px * 64 + (o ^ ((px & 7) << 3))] = f2bf(v);
                }
            }
        }
        __syncthreads();
        #pragma unroll
        for (int it = 0; it < 8; ++it) {
            int tau = tid + it * 128;
            int row = tau >> 8;
            int px = (tau >> 3) & 31;
            int j = tau & 7;
            short8 v = *(const short8*)(tl + row * 2048 + px * 64 + ((j ^ (px & 7)) * 8));
            *(short8*)(Tp + ((size_t)b * PXP_ + (size_t)(gh0 + row + 1) * WP_ +
                             (w0 + 1 + px)) * 64 + j * 8) = v;
        }
    } else {
        // ---- epilogue: residual add from X1p (bf16, L3-hot) + f32x4 out
        const unsigned short* Xr = Xres + (size_t)b * PXP_ * 64;
        #pragma unroll
        for (int nf = 0; nf < 2; ++nf) {
            int o = nf * 32 + ln31;
            float bi = bias[b * 64 + o];
            #pragma unroll
            for (int mf = 0; mf < 2; ++mf) {
                int gh = gh0 + 2 * wv + mf;
                #pragma unroll
                for (int k = 0; k < 4; ++k) {
                    int gw = w0 + 8 * k + 4 * g2;
                    size_t idx = ((size_t)b * 64 + o) * HW_ + (size_t)gh * W_ + gw;
                    const unsigned short* xr =
                        Xr + ((size_t)(gh + 1) * WP_ + (gw + 1)) * 64 + o;
                    f32x4 ov;
                    #pragma unroll
                    for (int q = 0; q < 4; ++q)
                        ov[q] = bf2f(xr[(size_t)q * 64]) + acc[mf][nf][4 * k + q] + bi;
                    *(f32x4*)(Fout + idx) = ov;
                }
            }
        }
    }
}

extern "C" void kernel_launch(void* const* d_in, const int* in_sizes, int n_in,
                              void* d_out, int out_size, void* d_ws, size_t ws_size,
                              hipStream_t stream) {
    const float* x     = (const float*)d_in[0];
    const float* attn  = (const float*)d_in[1];
    const float* gamma = (const float*)d_in[2];
    const float* par   = (const float*)d_in[3];
    const float* w1    = (const float*)d_in[4];
    const float* b1    = (const float*)d_in[5];
    const float* w2    = (const float*)d_in[6];
    const float* b2    = (const float*)d_in[7];
    const float* w16   = (const float*)d_in[8];
    const float* w168  = (const float*)d_in[9];
    const float* w88   = (const float*)d_in[10];
    float* out = (float*)d_out;

    char* w = (char*)d_ws;
    unsigned short* W4_1 = (unsigned short*)w;                        // 786432 B
    unsigned short* W4_2 = (unsigned short*)(w + 786432);             // 589824 B
    float* bias1 = (float*)(w + 786432 + 589824);                     // 2048 B
    float* bias2 = (float*)(w + 786432 + 589824 + 2048);              // 2048 B
    unsigned short* X1p = (unsigned short*)(w + 1380352);             // 68161536 B
    unsigned short* Tp  = (unsigned short*)(w + 1380352 + 68161536);  // 68161536 B

    k_combine<<<dim3(2692), dim3(256), 0, stream>>>(attn, gamma, w1, b1, w2, b2,
                                                    w16, w168, w88, W4_1, W4_2, bias1, bias2);
    k_border<<<dim3(514), dim3(256), 0, stream>>>(X1p, Tp);
    k_prep<<<dim3(1024, 8), dim3(256), 0, stream>>>(x, X1p);

    dim3 grid(512, 8);
    k_conv<1><<<grid, dim3(128), 0, stream>>>(X1p, nullptr, par, W4_1, bias1, Tp, nullptr);
    k_conv<2><<<grid, dim3(128), 0, stream>>>(Tp, X1p, par, W4_2, bias2, nullptr, out);
}

// Round 16
// 178.236 us; speedup vs baseline: 1.1040x; 1.1040x over previous
//
#include <hip/hip_runtime.h>
#include <hip/hip_bf16.h>

typedef __attribute__((ext_vector_type(8))) short short8;
typedef __attribute__((ext_vector_type(4))) float f32x4;

#define B_ 8
#define C_ 64
#define H_ 256
#define W_ 256
#define HW_ 65536
#define K_ 10
#define NS1 24
#define NS2 18
#define HP_ 258
#define WP_ 258
#define PXP_ (HP_*WP_)
#define SLABW 34
#define SLABR 6

static __device__ __forceinline__ unsigned short f2bf(float f) {
    __hip_bfloat16 hb = __float2bfloat16(f);
    return *(unsigned short*)&hb;
}
static __device__ __forceinline__ float bf2f(unsigned short u) {
    unsigned v = ((unsigned)u) << 16;
    float f;
    __builtin_memcpy(&f, &v, 4);
    return f;
}

// async global->LDS 16B (dest = wave-uniform base + lane*16, linear in tau)
static __device__ __forceinline__ void gload_lds16(const void* g, void* l) {
    __builtin_amdgcn_global_load_lds(
        (const __attribute__((address_space(1))) unsigned int*)(unsigned long long)g,
        (__attribute__((address_space(3))) unsigned int*)(unsigned int)(unsigned long long)l,
        16, 0, 0);
}

// iteration-order maps for the conv K-loop: dw outer in order {0,2,1} so the
// LAST dw-group (dw=1) leaves the center-tap A-frags cached for the par steps.
__device__ __host__ constexpr int SDW(int ii) {
    return (ii / 6 == 0) ? 0 : ((ii / 6 == 1) ? 2 : 1);
}
__device__ __host__ constexpr int SDH(int ii) { return (ii % 6) / 2; }
__device__ __host__ constexpr int SH(int ii)  { return ii & 1; }
__device__ __host__ constexpr int SS(int ii)  {
    return ii < 18 ? (3 * SDH(ii) + SDW(ii)) * 2 + SH(ii) : ii;
}

// ---------------------------------------------------------------------------
// Fragment-ordered, gamma-folded, expert-mixed weights + biases (R13 layout).
// W4_1: [b][24 steps][4 of][64 lane][8] bf16 (0..17 conv taps, 18..23 1x1)
// W4_2: [b][18 steps][4][64][8] bf16
// ---------------------------------------------------------------------------
__global__ void k_combine(const float* __restrict__ attn, const float* __restrict__ gamma,
                          const float* __restrict__ w1, const float* __restrict__ b1,
                          const float* __restrict__ w2, const float* __restrict__ b2,
                          const float* __restrict__ w16, const float* __restrict__ w168,
                          const float* __restrict__ w88,
                          unsigned short* __restrict__ W4_1, unsigned short* __restrict__ W4_2,
                          float* __restrict__ bias1, float* __restrict__ bias2) {
    const int N1 = B_ * NS1 * 2048;
    const int N2 = B_ * NS2 * 2048;
    int gid = blockIdx.x * 256 + threadIdx.x;
    if (gid < N1) {
        int b = gid / (NS1 * 2048);
        int r = gid - b * (NS1 * 2048);
        int s = r >> 11;
        int r2 = r & 2047;
        int of = r2 >> 9, l = (r2 >> 3) & 63, j = r2 & 7;
        int o = of * 16 + (l & 15);
        int g = l >> 4;
        float val;
        if (s < 18) {
            int t = s >> 1, h = s & 1;
            int c = h * 32 + g * 8 + j;
            float acc = 0.f;
            #pragma unroll
            for (int k = 0; k < K_; ++k)
                acc += attn[b * K_ + k] * w2[((size_t)(k * 64 + o) * 64 + c) * 9 + t];
            val = acc * gamma[b * 64 + o];
        } else {
            int e = s - 18;
            int m = e >> 1, h = e & 1;
            int c = h * 32 + g * 8 + j;
            const float* wm = (m == 0) ? w16 : (m == 1 ? w168 : w88);
            val = wm[o * 64 + c];
        }
        W4_1[gid] = f2bf(val);
    } else if (gid < N1 + N2) {
        int gid2 = gid - N1;
        int b = gid2 / (NS2 * 2048);
        int r = gid2 - b * (NS2 * 2048);
        int s = r >> 11;
        int r2 = r & 2047;
        int of = r2 >> 9, l = (r2 >> 3) & 63, j = r2 & 7;
        int o = of * 16 + (l & 15);
        int g = l >> 4;
        int t = s >> 1, h = s & 1;
        int c = h * 32 + g * 8 + j;
        float acc = 0.f;
        #pragma unroll
        for (int k = 0; k < K_; ++k)
            acc += attn[b * K_ + k] * w1[((size_t)(k * 64 + o) * 64 + c) * 9 + t];
        W4_2[gid2] = f2bf(acc * gamma[b * 64 + o]);
    } else if (gid < N1 + N2 + 1024) {
        int id2 = gid - N1 - N2;
        int b = id2 >> 7;
        int rest = id2 & 127;
        int o = rest >> 1;
        int which = rest & 1;
        const float* bb = which ? b1 : b2;
        float acc = 0.f;
        #pragma unroll
        for (int k = 0; k < K_; ++k) acc += attn[b * K_ + k] * bb[k * 64 + o];
        float v = acc * gamma[b * 64 + o];
        if (which) bias2[b * 64 + o] = v; else bias1[b * 64 + o] = v;
    }
}

// ---------------------------------------------------------------------------
// Zero halo borders of the padded X1p / Tp buffers.
// ---------------------------------------------------------------------------
__global__ void k_border(unsigned short* __restrict__ X1p, unsigned short* __restrict__ Tp) {
    int gid = blockIdx.x * 256 + threadIdx.x;
    if (gid >= 2 * B_ * 1028 * 8) return;
    int chunk = gid & 7;
    int rest = gid >> 3;
    int p = rest % 1028;
    int rb = rest / 1028;
    int buf = rb & 1, b = rb >> 1;
    int row, col;
    if (p < 258) { row = 0; col = p; }
    else if (p < 516) { row = 257; col = p - 258; }
    else if (p < 772) { row = p - 516 + 1; col = 0; }
    else { row = p - 772 + 1; col = 257; }
    unsigned short* base = (buf ? Tp : X1p) +
        ((size_t)b * PXP_ + (size_t)row * WP_ + col) * 64 + chunk * 8;
    *(short8*)base = (short8){0, 0, 0, 0, 0, 0, 0, 0};
}

// ---------------------------------------------------------------------------
// x [b][64][HW] f32  ->  X1p [b][258][258][64] bf16 (interior only).
// Vectorized: f32x4 global loads, short8 global stores (LDS transpose).
// ---------------------------------------------------------------------------
__global__ __launch_bounds__(256) void k_prep(const float* __restrict__ x,
                                              unsigned short* __restrict__ X1p) {
    __shared__ float ls[64][65];
    const int b = blockIdx.y;
    const int px0 = blockIdx.x * 64;
    const int row = px0 >> 8;
    const int col0 = px0 & 255;
    const int t = threadIdx.x;
    #pragma unroll
    for (int it = 0; it < 4; ++it) {
        int e = t + it * 256;           // 0..1023: ch = e>>4, 4-px group = e&15
        int ch = e >> 4, q = e & 15;
        f32x4 v = *(const f32x4*)(x + ((size_t)(b * 64 + ch)) * HW_ + px0 + q * 4);
        ls[ch][q * 4 + 0] = v[0];
        ls[ch][q * 4 + 1] = v[1];
        ls[ch][q * 4 + 2] = v[2];
        ls[ch][q * 4 + 3] = v[3];
    }
    __syncthreads();
    unsigned short* dst = X1p + ((size_t)b * PXP_ + (size_t)(row + 1) * WP_ + col0 + 1) * 64;
    #pragma unroll
    for (int k = 0; k < 2; ++k) {
        int c = t + k * 256;            // 0..511: px = c>>3, ch-chunk = c&7
        int px = c >> 3, ch0 = (c & 7) * 8;
        short8 v8;
        #pragma unroll
        for (int j = 0; j < 8; ++j) v8[j] = (short)f2bf(ls[ch0 + j][px]);
        *(short8*)(dst + (size_t)px * 64 + ch0) = v8;
    }
}

// ---------------------------------------------------------------------------
// Implicit-GEMM conv3x3 via MFMA 16x16x32 (R13 skeleton + dh-row caching).
// Block: 128 thr / 2 FAT waves; wave owns M=64 px (2 rows x 32 px), N=64 o.
// K-loop iterated dw-outer (order {0,2,1}): within one dw the three dh taps
// share A rows -> A ds_reads 72->48; ending at dw=1 leaves center-tap frags
// cached for the par-expert steps (their 24 reads -> 0). Total LDS -25%.
// A: slab [6][34][64] via global_load_lds. B: 3-slot x 4KB ring, staged in
// iteration order, distance 2, counted vmcnt (never drain-0), raw s_barrier.
// 4 independent blocks/CU, 2 waves/SIMD.
// ---------------------------------------------------------------------------
template<int STAGE>
__global__ __launch_bounds__(128, 2) void k_conv(
    const unsigned short* __restrict__ Xp,    // A source [b][258][258][64] bf16 padded
    const unsigned short* __restrict__ Xres,  // stage2 residual (X1p, bf16 padded)
    const float* __restrict__ par,            // stage1 [b][3][HW]
    const unsigned short* __restrict__ W4,    // [b][NS][4][64][8] bf16
    const float* __restrict__ bias,           // [b][64]
    unsigned short* __restrict__ Tp,          // stage1 out [b][258][258][64] bf16
    float* __restrict__ Fout)                 // stage2 out [b][64][HW] f32
{
    constexpr int NS = (STAGE == 1) ? NS1 : NS2;
    __shared__ short xs[SLABR * SLABW * 64];  // 26112 B (aliased as tl in epilogue)
    __shared__ short bring[3 * 2048];         // 12288 B B-ring (3 slots x 4KB)

    const int tid = threadIdx.x;
    const int l = tid & 63;
    const int wv = tid >> 6;                  // 0..1; wave owns rows 2wv, 2wv+1
    const int b = blockIdx.y;
    // XCD-aware bijective swizzle (512 blocks = 8 XCD x 64)
    const int bswz = (blockIdx.x & 7) * 64 + (blockIdx.x >> 3);
    const int rblk = bswz >> 3;               // 0..63
    const int cblk = bswz & 7;                // 0..7
    const int gh0 = rblk * 4, w0 = cblk * 32;
    const int ln15 = l & 15, g = l >> 4;

    const char* XbP = (const char*)Xp + (size_t)b * PXP_ * 128;
    const unsigned short* Wb = W4 + (size_t)b * (NS * 2048);

    // par values first (oldest in vm queue; drained by the prologue fence)
    float pvv[3][4];
    if constexpr (STAGE == 1) {
        #pragma unroll
        for (int m = 0; m < 3; ++m)
            #pragma unroll
            for (int mf = 0; mf < 4; ++mf)
                pvv[m][mf] = par[((size_t)b * 3 + m) * HW_ +
                                 (gh0 + 2 * wv + (mf >> 1)) * W_ + w0 + 16 * (mf & 1) + ln15];
    }

    f32x4 acc[4][4];
    #pragma unroll
    for (int mf = 0; mf < 4; ++mf)
        #pragma unroll
        for (int of = 0; of < 4; ++of)
            acc[mf][of] = (f32x4){0.f, 0.f, 0.f, 0.f};

    // ---- async-stage slab [6 rows][34 px][8 chunks]; swizzled src, linear dest
    #pragma unroll
    for (int it = 0; it < 13; ++it) {
        int tau = tid + it * 128;
        if (tau < SLABR * SLABW * 8) {
            int slot = tau & 7;
            int rest = tau >> 3;
            int px = rest % SLABW;
            int row = rest / SLABW;
            int cb = slot ^ (px & 7);
            gload_lds16(XbP + ((size_t)(gh0 + row) * WP_ + (w0 + px)) * 128 + cb * 16,
                        (char*)xs + (size_t)tau * 16);
        }
    }
    // ---- B stage by ring index ii (data from step SS(ii)); 2 gloads/thread
    auto stage_b = [&](int ii) {
        const char* src = (const char*)Wb + (size_t)SS(ii) * 4096;
        char* dst = (char*)bring + (ii % 3) * 4096;
        gload_lds16(src + tid * 16, dst + tid * 16);
        gload_lds16(src + 2048 + tid * 16, dst + 2048 + tid * 16);
    };
    stage_b(0);
    stage_b(1);

    // A-frag read: slab row 2wv+ro, px-half ph, K-half hh, tap column dw
    auto ldA = [&](int ro, int ph, int hh, int dw) -> short8 {
        int idx = 16 * ph + ln15 + dw;
        int rowx = 2 * wv + ro;
        return *(const short8*)((const char*)xs + (rowx * SLABW + idx) * 128 +
                                ((((hh << 2) | g) ^ (idx & 7)) << 4));
    };

    // prologue: slab + B(0) landed; B(1) (2 gloads) stays in flight
    asm volatile("s_waitcnt vmcnt(2)" ::: "memory");
    __builtin_amdgcn_s_barrier();

    short8 ca[4][2][2];   // [row-offset 0..3][px-half][K-half] - all static idx

    #pragma unroll
    for (int ii = 0; ii < 18; ++ii) {
        const int dw = SDW(ii), dh = SDH(ii), hh = SH(ii);
        if (ii + 2 < NS) stage_b(ii + 2);
        // B frags from ring slot ii%3 (contiguous 1KB per of -> conflict-free)
        const char* rb = (const char*)bring + (ii % 3) * 4096 + (size_t)l * 16;
        short8 bf0 = *(const short8*)(rb);
        short8 bf1 = *(const short8*)(rb + 1024);
        short8 bf2 = *(const short8*)(rb + 2048);
        short8 bf3 = *(const short8*)(rb + 3072);
        // A loads: dh==0 loads rows 0,1 for this hh; dh>=1 adds row dh+1
        if (dh == 0) {
            ca[0][0][hh] = ldA(0, 0, hh, dw);
            ca[0][1][hh] = ldA(0, 1, hh, dw);
            ca[1][0][hh] = ldA(1, 0, hh, dw);
            ca[1][1][hh] = ldA(1, 1, hh, dw);
        } else {
            ca[dh + 1][0][hh] = ldA(dh + 1, 0, hh, dw);
            ca[dh + 1][1][hh] = ldA(dh + 1, 1, hh, dw);
        }
        __builtin_amdgcn_s_setprio(1);
        #pragma unroll
        for (int mf = 0; mf < 4; ++mf) {
            short8 a = ca[(mf >> 1) + dh][mf & 1][hh];
            acc[mf][0] = __builtin_amdgcn_mfma_f32_16x16x32_bf16(a, bf0, acc[mf][0], 0, 0, 0);
            acc[mf][1] = __builtin_amdgcn_mfma_f32_16x16x32_bf16(a, bf1, acc[mf][1], 0, 0, 0);
            acc[mf][2] = __builtin_amdgcn_mfma_f32_16x16x32_bf16(a, bf2, acc[mf][2], 0, 0, 0);
            acc[mf][3] = __builtin_amdgcn_mfma_f32_16x16x32_bf16(a, bf3, acc[mf][3], 0, 0, 0);
        }
        __builtin_amdgcn_s_setprio(0);
        if (ii + 1 < NS) {
            if (ii + 2 < NS) asm volatile("s_waitcnt vmcnt(2)" ::: "memory");
            else             asm volatile("s_waitcnt vmcnt(0)" ::: "memory");
            __builtin_amdgcn_s_barrier();
        }
    }

    if constexpr (STAGE == 1) {
        // par-expert steps: center-tap A-frags (dw=1, rows 1,2) are STILL in ca
        // because the conv loop ended on the dw=1 group.
        #pragma unroll
        for (int ii = 18; ii < 24; ++ii) {
            const int e = ii - 18, m = e >> 1, hh = e & 1;
            if (ii + 2 < NS1) stage_b(ii + 2);
            const char* rb = (const char*)bring + (ii % 3) * 4096 + (size_t)l * 16;
            short8 bf0 = *(const short8*)(rb);
            short8 bf1 = *(const short8*)(rb + 1024);
            short8 bf2 = *(const short8*)(rb + 2048);
            short8 bf3 = *(const short8*)(rb + 3072);
            short8 sa[4];
            #pragma unroll
            for (int mf = 0; mf < 4; ++mf) {
                short8 base = ca[(mf >> 1) + 1][mf & 1][hh];
                #pragma unroll
                for (int j = 0; j < 8; ++j)
                    sa[mf][j] = (short)f2bf(bf2f((unsigned short)base[j]) * pvv[m][mf]);
            }
            __builtin_amdgcn_s_setprio(1);
            #pragma unroll
            for (int mf = 0; mf < 4; ++mf) {
                acc[mf][0] = __builtin_amdgcn_mfma_f32_16x16x32_bf16(sa[mf], bf0, acc[mf][0], 0, 0, 0);
                acc[mf][1] = __builtin_amdgcn_mfma_f32_16x16x32_bf16(sa[mf], bf1, acc[mf][1], 0, 0, 0);
                acc[mf][2] = __builtin_amdgcn_mfma_f32_16x16x32_bf16(sa[mf], bf2, acc[mf][2], 0, 0, 0);
                acc[mf][3] = __builtin_amdgcn_mfma_f32_16x16x32_bf16(sa[mf], bf3, acc[mf][3], 0, 0, 0);
            }
            __builtin_amdgcn_s_setprio(0);
            if (ii + 1 < NS1) {
                if (ii + 2 < NS1) asm volatile("s_waitcnt vmcnt(2)" ::: "memory");
                else              asm volatile("s_waitcnt vmcnt(0)" ::: "memory");
                __builtin_amdgcn_s_barrier();
            }
        }

        // ---- epilogue: assemble 128B lines in slab-aliased LDS, store dwordx4
        __syncthreads();                       // all slab/ring reads done
        unsigned short* tl = (unsigned short*)xs;   // [4 rows][32 px][64 o^swz] = 16 KB
        #pragma unroll
        for (int of = 0; of < 4; ++of) {
            int o = of * 16 + ln15;
            float bi = bias[b * 64 + o];
            #pragma unroll
            for (int mf = 0; mf < 4; ++mf) {
                int row_local = 2 * wv + (mf >> 1);
                #pragma unroll
                for (int q = 0; q < 4; ++q) {
                    int px = 16 * (mf & 1) + 4 * g + q;
                    float v = fmaxf(acc[mf][of][q] + bi, 0.f);
                    tl[row_local * 2048 + px * 64 + (o ^ ((px & 7) << 3))] = f2bf(v);
                }
            }
        }
        __syncthreads();
        #pragma unroll
        for (int it = 0; it < 8; ++it) {
            int tau = tid + it * 128;
            int row = tau >> 8;
            int px = (tau >> 3) & 31;
            int j = tau & 7;
            short8 v = *(const short8*)(tl + row * 2048 + px * 64 + ((j ^ (px & 7)) * 8));
            *(short8*)(Tp + ((size_t)b * PXP_ + (size_t)(gh0 + row + 1) * WP_ +
                             (w0 + 1 + px)) * 64 + j * 8) = v;
        }
    } else {
        // ---- epilogue: residual add from X1p (bf16, L3-hot) + f32x4 out
        const unsigned short* Xr = Xres + (size_t)b * PXP_ * 64;
        #pragma unroll
        for (int of = 0; of < 4; ++of) {
            int o = of * 16 + ln15;
            float bi = bias[b * 64 + o];
            #pragma unroll
            for (int mf = 0; mf < 4; ++mf) {
                int gh = gh0 + 2 * wv + (mf >> 1);
                int gw = w0 + 16 * (mf & 1) + g * 4;
                size_t idx = ((size_t)b * 64 + o) * HW_ + (size_t)gh * W_ + gw;
                const unsigned short* xr =
                    Xr + ((size_t)(gh + 1) * WP_ + (gw + 1)) * 64 + o;
                f32x4 ov;
                #pragma unroll
                for (int q = 0; q < 4; ++q)
                    ov[q] = bf2f(xr[(size_t)q * 64]) + acc[mf][of][q] + bi;
                *(f32x4*)(Fout + idx) = ov;
            }
        }
    }
}

extern "C" void kernel_launch(void* const* d_in, const int* in_sizes, int n_in,
                              void* d_out, int out_size, void* d_ws, size_t ws_size,
                              hipStream_t stream) {
    const float* x     = (const float*)d_in[0];
    const float* attn  = (const float*)d_in[1];
    const float* gamma = (const float*)d_in[2];
    const float* par   = (const float*)d_in[3];
    const float* w1    = (const float*)d_in[4];
    const float* b1    = (const float*)d_in[5];
    const float* w2    = (const float*)d_in[6];
    const float* b2    = (const float*)d_in[7];
    const float* w16   = (const float*)d_in[8];
    const float* w168  = (const float*)d_in[9];
    const float* w88   = (const float*)d_in[10];
    float* out = (float*)d_out;

    char* w = (char*)d_ws;
    unsigned short* W4_1 = (unsigned short*)w;                        // 786432 B
    unsigned short* W4_2 = (unsigned short*)(w + 786432);             // 589824 B
    float* bias1 = (float*)(w + 786432 + 589824);                     // 2048 B
    float* bias2 = (float*)(w + 786432 + 589824 + 2048);              // 2048 B
    unsigned short* X1p = (unsigned short*)(w + 1380352);             // 68161536 B
    unsigned short* Tp  = (unsigned short*)(w + 1380352 + 68161536);  // 68161536 B

    k_combine<<<dim3(2692), dim3(256), 0, stream>>>(attn, gamma, w1, b1, w2, b2,
                                                    w16, w168, w88, W4_1, W4_2, bias1, bias2);
    k_border<<<dim3(514), dim3(256), 0, stream>>>(X1p, Tp);
    k_prep<<<dim3(1024, 8), dim3(256), 0, stream>>>(x, X1p);

    dim3 grid(512, 8);
    k_conv<1><<<grid, dim3(128), 0, stream>>>(X1p, nullptr, par, W4_1, bias1, Tp, nullptr);
    k_conv<2><<<grid, dim3(128), 0, stream>>>(Tp, X1p, par, W4_2, bias2, nullptr, out);
}

// Round 17
// 172.467 us; speedup vs baseline: 1.1410x; 1.0334x over previous
//
#include <hip/hip_runtime.h>
#include <hip/hip_bf16.h>

typedef __attribute__((ext_vector_type(8))) short short8;
typedef __attribute__((ext_vector_type(4))) float f32x4;

#define B_ 8
#define C_ 64
#define H_ 256
#define W_ 256
#define HW_ 65536
#define K_ 10
#define NS1 24
#define NS2 18
#define HP_ 258
#define WP_ 258
#define PXP_ (HP_*WP_)
#define SLABW 34
#define SLABR 6

// k_pre grid partition
#define NB_COMBINE 2692
#define NB_BORDER  514
#define NB_PREP    8192

static __device__ __forceinline__ unsigned short f2bf(float f) {
    __hip_bfloat16 hb = __float2bfloat16(f);
    return *(unsigned short*)&hb;
}
static __device__ __forceinline__ float bf2f(unsigned short u) {
    unsigned v = ((unsigned)u) << 16;
    float f;
    __builtin_memcpy(&f, &v, 4);
    return f;
}

// async global->LDS 16B (dest = wave-uniform base + lane*16, linear in tau)
static __device__ __forceinline__ void gload_lds16(const void* g, void* l) {
    __builtin_amdgcn_global_load_lds(
        (const __attribute__((address_space(1))) unsigned int*)(unsigned long long)g,
        (__attribute__((address_space(3))) unsigned int*)(unsigned int)(unsigned long long)l,
        16, 0, 0);
}

// iteration-order maps for the conv K-loop: dw outer in order {0,2,1} so the
// LAST dw-group (dw=1) leaves the center-tap A-frags cached for the par steps.
__device__ __host__ constexpr int SDW(int ii) {
    return (ii / 6 == 0) ? 0 : ((ii / 6 == 1) ? 2 : 1);
}
__device__ __host__ constexpr int SDH(int ii) { return (ii % 6) / 2; }
__device__ __host__ constexpr int SH(int ii)  { return ii & 1; }
__device__ __host__ constexpr int SS(int ii)  {
    return ii < 18 ? (3 * SDH(ii) + SDW(ii)) * 2 + SH(ii) : ii;
}

// ---------------------------------------------------------------------------
// Merged pre-pass: combine (expert-mix weights) + border-zero + prep
// (x -> padded bf16 px-major). Independent roles dispatched by block range so
// the small combine/border work hides under the BW-bound prep blocks.
// ---------------------------------------------------------------------------
__global__ __launch_bounds__(256) void k_pre(
    const float* __restrict__ x,
    const float* __restrict__ attn, const float* __restrict__ gamma,
    const float* __restrict__ w1, const float* __restrict__ b1,
    const float* __restrict__ w2, const float* __restrict__ b2,
    const float* __restrict__ w16, const float* __restrict__ w168,
    const float* __restrict__ w88,
    unsigned short* __restrict__ W4_1, unsigned short* __restrict__ W4_2,
    float* __restrict__ bias1, float* __restrict__ bias2,
    unsigned short* __restrict__ X1p, unsigned short* __restrict__ Tp)
{
    __shared__ float ls[64][65];
    const int bx = blockIdx.x;
    const int t = threadIdx.x;

    if (bx < NB_COMBINE) {
        // ---------------- combine: fragment-ordered, gamma-folded weights
        const int N1 = B_ * NS1 * 2048;
        const int N2 = B_ * NS2 * 2048;
        int gid = bx * 256 + t;
        if (gid < N1) {
            int b = gid / (NS1 * 2048);
            int r = gid - b * (NS1 * 2048);
            int s = r >> 11;
            int r2 = r & 2047;
            int of = r2 >> 9, l = (r2 >> 3) & 63, j = r2 & 7;
            int o = of * 16 + (l & 15);
            int g = l >> 4;
            float val;
            if (s < 18) {
                int tp = s >> 1, h = s & 1;
                int c = h * 32 + g * 8 + j;
                float acc = 0.f;
                #pragma unroll
                for (int k = 0; k < K_; ++k)
                    acc += attn[b * K_ + k] * w2[((size_t)(k * 64 + o) * 64 + c) * 9 + tp];
                val = acc * gamma[b * 64 + o];
            } else {
                int e = s - 18;
                int m = e >> 1, h = e & 1;
                int c = h * 32 + g * 8 + j;
                const float* wm = (m == 0) ? w16 : (m == 1 ? w168 : w88);
                val = wm[o * 64 + c];
            }
            W4_1[gid] = f2bf(val);
        } else if (gid < N1 + N2) {
            int gid2 = gid - N1;
            int b = gid2 / (NS2 * 2048);
            int r = gid2 - b * (NS2 * 2048);
            int s = r >> 11;
            int r2 = r & 2047;
            int of = r2 >> 9, l = (r2 >> 3) & 63, j = r2 & 7;
            int o = of * 16 + (l & 15);
            int g = l >> 4;
            int tp = s >> 1, h = s & 1;
            int c = h * 32 + g * 8 + j;
            float acc = 0.f;
            #pragma unroll
            for (int k = 0; k < K_; ++k)
                acc += attn[b * K_ + k] * w1[((size_t)(k * 64 + o) * 64 + c) * 9 + tp];
            W4_2[gid2] = f2bf(acc * gamma[b * 64 + o]);
        } else if (gid < N1 + N2 + 1024) {
            int id2 = gid - N1 - N2;
            int b = id2 >> 7;
            int rest = id2 & 127;
            int o = rest >> 1;
            int which = rest & 1;
            const float* bb = which ? b1 : b2;
            float acc = 0.f;
            #pragma unroll
            for (int k = 0; k < K_; ++k) acc += attn[b * K_ + k] * bb[k * 64 + o];
            float v = acc * gamma[b * 64 + o];
            if (which) bias2[b * 64 + o] = v; else bias1[b * 64 + o] = v;
        }
    } else if (bx < NB_COMBINE + NB_BORDER) {
        // ---------------- border zeroing of X1p / Tp halos
        int gid = (bx - NB_COMBINE) * 256 + t;
        if (gid >= 2 * B_ * 1028 * 8) return;
        int chunk = gid & 7;
        int rest = gid >> 3;
        int p = rest % 1028;
        int rb = rest / 1028;
        int buf = rb & 1, b = rb >> 1;
        int row, col;
        if (p < 258) { row = 0; col = p; }
        else if (p < 516) { row = 257; col = p - 258; }
        else if (p < 772) { row = p - 516 + 1; col = 0; }
        else { row = p - 772 + 1; col = 257; }
        unsigned short* base = (buf ? Tp : X1p) +
            ((size_t)b * PXP_ + (size_t)row * WP_ + col) * 64 + chunk * 8;
        *(short8*)base = (short8){0, 0, 0, 0, 0, 0, 0, 0};
    } else {
        // ---------------- prep: x [b][64][HW] f32 -> X1p padded bf16 px-major
        int pb = bx - (NB_COMBINE + NB_BORDER);
        const int b = pb >> 10;
        const int px0 = (pb & 1023) * 64;
        const int row = px0 >> 8;
        const int col0 = px0 & 255;
        #pragma unroll
        for (int it = 0; it < 4; ++it) {
            int e = t + it * 256;           // ch = e>>4, 4-px group = e&15
            int ch = e >> 4, q = e & 15;
            f32x4 v = *(const f32x4*)(x + ((size_t)(b * 64 + ch)) * HW_ + px0 + q * 4);
            ls[ch][q * 4 + 0] = v[0];
            ls[ch][q * 4 + 1] = v[1];
            ls[ch][q * 4 + 2] = v[2];
            ls[ch][q * 4 + 3] = v[3];
        }
        __syncthreads();
        unsigned short* dst = X1p + ((size_t)b * PXP_ + (size_t)(row + 1) * WP_ + col0 + 1) * 64;
        #pragma unroll
        for (int k = 0; k < 2; ++k) {
            int c = t + k * 256;            // px = c>>3, ch-chunk = c&7
            int px = c >> 3, ch0 = (c & 7) * 8;
            short8 v8;
            #pragma unroll
            for (int j = 0; j < 8; ++j) v8[j] = (short)f2bf(ls[ch0 + j][px]);
            *(short8*)(dst + (size_t)px * 64 + ch0) = v8;
        }
    }
}

// ---------------------------------------------------------------------------
// Implicit-GEMM conv3x3 via MFMA 16x16x32 (R16: R13 skeleton + dh-row cache).
// Block: 128 thr / 2 FAT waves; wave owns M=64 px (2 rows x 32 px), N=64 o.
// A: slab [6][34][64] via global_load_lds. B: 3-slot x 4KB ring, staged in
// iteration order, distance 2, counted vmcnt (never drain-0), raw s_barrier.
// 4 independent blocks/CU, 2 waves/SIMD.
// ---------------------------------------------------------------------------
template<int STAGE>
__global__ __launch_bounds__(128, 2) void k_conv(
    const unsigned short* __restrict__ Xp,    // A source [b][258][258][64] bf16 padded
    const unsigned short* __restrict__ Xres,  // stage2 residual (X1p, bf16 padded)
    const float* __restrict__ par,            // stage1 [b][3][HW]
    const unsigned short* __restrict__ W4,    // [b][NS][4][64][8] bf16
    const float* __restrict__ bias,           // [b][64]
    unsigned short* __restrict__ Tp,          // stage1 out [b][258][258][64] bf16
    float* __restrict__ Fout)                 // stage2 out [b][64][HW] f32
{
    constexpr int NS = (STAGE == 1) ? NS1 : NS2;
    __shared__ short xs[SLABR * SLABW * 64];  // 26112 B (aliased as tl in epilogue)
    __shared__ short bring[3 * 2048];         // 12288 B B-ring (3 slots x 4KB)

    const int tid = threadIdx.x;
    const int l = tid & 63;
    const int wv = tid >> 6;                  // 0..1; wave owns rows 2wv, 2wv+1
    const int b = blockIdx.y;
    // XCD-aware bijective swizzle (512 blocks = 8 XCD x 64)
    const int bswz = (blockIdx.x & 7) * 64 + (blockIdx.x >> 3);
    const int rblk = bswz >> 3;               // 0..63
    const int cblk = bswz & 7;                // 0..7
    const int gh0 = rblk * 4, w0 = cblk * 32;
    const int ln15 = l & 15, g = l >> 4;

    const char* XbP = (const char*)Xp + (size_t)b * PXP_ * 128;
    const unsigned short* Wb = W4 + (size_t)b * (NS * 2048);

    // par values first (oldest in vm queue; drained by the prologue fence)
    float pvv[3][4];
    if constexpr (STAGE == 1) {
        #pragma unroll
        for (int m = 0; m < 3; ++m)
            #pragma unroll
            for (int mf = 0; mf < 4; ++mf)
                pvv[m][mf] = par[((size_t)b * 3 + m) * HW_ +
                                 (gh0 + 2 * wv + (mf >> 1)) * W_ + w0 + 16 * (mf & 1) + ln15];
    }

    f32x4 acc[4][4];
    #pragma unroll
    for (int mf = 0; mf < 4; ++mf)
        #pragma unroll
        for (int of = 0; of < 4; ++of)
            acc[mf][of] = (f32x4){0.f, 0.f, 0.f, 0.f};

    // ---- async-stage slab [6 rows][34 px][8 chunks]; swizzled src, linear dest
    #pragma unroll
    for (int it = 0; it < 13; ++it) {
        int tau = tid + it * 128;
        if (tau < SLABR * SLABW * 8) {
            int slot = tau & 7;
            int rest = tau >> 3;
            int px = rest % SLABW;
            int row = rest / SLABW;
            int cb = slot ^ (px & 7);
            gload_lds16(XbP + ((size_t)(gh0 + row) * WP_ + (w0 + px)) * 128 + cb * 16,
                        (char*)xs + (size_t)tau * 16);
        }
    }
    // ---- B stage by ring index ii (data from step SS(ii)); 2 gloads/thread
    auto stage_b = [&](int ii) {
        const char* src = (const char*)Wb + (size_t)SS(ii) * 4096;
        char* dst = (char*)bring + (ii % 3) * 4096;
        gload_lds16(src + tid * 16, dst + tid * 16);
        gload_lds16(src + 2048 + tid * 16, dst + 2048 + tid * 16);
    };
    stage_b(0);
    stage_b(1);

    // A-frag read: slab row 2wv+ro, px-half ph, K-half hh, tap column dw
    auto ldA = [&](int ro, int ph, int hh, int dw) -> short8 {
        int idx = 16 * ph + ln15 + dw;
        int rowx = 2 * wv + ro;
        return *(const short8*)((const char*)xs + (rowx * SLABW + idx) * 128 +
                                ((((hh << 2) | g) ^ (idx & 7)) << 4));
    };

    // prologue: slab + B(0) landed; B(1) (2 gloads) stays in flight
    asm volatile("s_waitcnt vmcnt(2)" ::: "memory");
    __builtin_amdgcn_s_barrier();

    short8 ca[4][2][2];   // [row-offset 0..3][px-half][K-half] - all static idx

    #pragma unroll
    for (int ii = 0; ii < 18; ++ii) {
        const int dw = SDW(ii), dh = SDH(ii), hh = SH(ii);
        if (ii + 2 < NS) stage_b(ii + 2);
        // B frags from ring slot ii%3 (contiguous 1KB per of -> conflict-free)
        const char* rb = (const char*)bring + (ii % 3) * 4096 + (size_t)l * 16;
        short8 bf0 = *(const short8*)(rb);
        short8 bf1 = *(const short8*)(rb + 1024);
        short8 bf2 = *(const short8*)(rb + 2048);
        short8 bf3 = *(const short8*)(rb + 3072);
        // A loads: dh==0 loads rows 0,1 for this hh; dh>=1 adds row dh+1
        if (dh == 0) {
            ca[0][0][hh] = ldA(0, 0, hh, dw);
            ca[0][1][hh] = ldA(0, 1, hh, dw);
            ca[1][0][hh] = ldA(1, 0, hh, dw);
            ca[1][1][hh] = ldA(1, 1, hh, dw);
        } else {
            ca[dh + 1][0][hh] = ldA(dh + 1, 0, hh, dw);
            ca[dh + 1][1][hh] = ldA(dh + 1, 1, hh, dw);
        }
        __builtin_amdgcn_s_setprio(1);
        #pragma unroll
        for (int mf = 0; mf < 4; ++mf) {
            short8 a = ca[(mf >> 1) + dh][mf & 1][hh];
            acc[mf][0] = __builtin_amdgcn_mfma_f32_16x16x32_bf16(a, bf0, acc[mf][0], 0, 0, 0);
            acc[mf][1] = __builtin_amdgcn_mfma_f32_16x16x32_bf16(a, bf1, acc[mf][1], 0, 0, 0);
            acc[mf][2] = __builtin_amdgcn_mfma_f32_16x16x32_bf16(a, bf2, acc[mf][2], 0, 0, 0);
            acc[mf][3] = __builtin_amdgcn_mfma_f32_16x16x32_bf16(a, bf3, acc[mf][3], 0, 0, 0);
        }
        __builtin_amdgcn_s_setprio(0);
        if (ii + 1 < NS) {
            if (ii + 2 < NS) asm volatile("s_waitcnt vmcnt(2)" ::: "memory");
            else             asm volatile("s_waitcnt vmcnt(0)" ::: "memory");
            __builtin_amdgcn_s_barrier();
        }
    }

    if constexpr (STAGE == 1) {
        // par-expert steps: center-tap A-frags (dw=1, rows 1,2) are STILL in ca
        // because the conv loop ended on the dw=1 group.
        #pragma unroll
        for (int ii = 18; ii < 24; ++ii) {
            const int e = ii - 18, m = e >> 1, hh = e & 1;
            if (ii + 2 < NS1) stage_b(ii + 2);
            const char* rb = (const char*)bring + (ii % 3) * 4096 + (size_t)l * 16;
            short8 bf0 = *(const short8*)(rb);
            short8 bf1 = *(const short8*)(rb + 1024);
            short8 bf2 = *(const short8*)(rb + 2048);
            short8 bf3 = *(const short8*)(rb + 3072);
            short8 sa[4];
            #pragma unroll
            for (int mf = 0; mf < 4; ++mf) {
                short8 base = ca[(mf >> 1) + 1][mf & 1][hh];
                #pragma unroll
                for (int j = 0; j < 8; ++j)
                    sa[mf][j] = (short)f2bf(bf2f((unsigned short)base[j]) * pvv[m][mf]);
            }
            __builtin_amdgcn_s_setprio(1);
            #pragma unroll
            for (int mf = 0; mf < 4; ++mf) {
                acc[mf][0] = __builtin_amdgcn_mfma_f32_16x16x32_bf16(sa[mf], bf0, acc[mf][0], 0, 0, 0);
                acc[mf][1] = __builtin_amdgcn_mfma_f32_16x16x32_bf16(sa[mf], bf1, acc[mf][1], 0, 0, 0);
                acc[mf][2] = __builtin_amdgcn_mfma_f32_16x16x32_bf16(sa[mf], bf2, acc[mf][2], 0, 0, 0);
                acc[mf][3] = __builtin_amdgcn_mfma_f32_16x16x32_bf16(sa[mf], bf3, acc[mf][3], 0, 0, 0);
            }
            __builtin_amdgcn_s_setprio(0);
            if (ii + 1 < NS1) {
                if (ii + 2 < NS1) asm volatile("s_waitcnt vmcnt(2)" ::: "memory");
                else              asm volatile("s_waitcnt vmcnt(0)" ::: "memory");
                __builtin_amdgcn_s_barrier();
            }
        }

        // ---- epilogue: assemble 128B lines in slab-aliased LDS, store dwordx4
        __syncthreads();                       // all slab/ring reads done
        unsigned short* tl = (unsigned short*)xs;   // [4 rows][32 px][64 o^swz] = 16 KB
        #pragma unroll
        for (int of = 0; of < 4; ++of) {
            int o = of * 16 + ln15;
            float bi = bias[b * 64 + o];
            #pragma unroll
            for (int mf = 0; mf < 4; ++mf) {
                int row_local = 2 * wv + (mf >> 1);
                #pragma unroll
                for (int q = 0; q < 4; ++q) {
                    int px = 16 * (mf & 1) + 4 * g + q;
                    float v = fmaxf(acc[mf][of][q] + bi, 0.f);
                    tl[row_local * 2048 + px * 64 + (o ^ ((px & 7) << 3))] = f2bf(v);
                }
            }
        }
        __syncthreads();
        #pragma unroll
        for (int it = 0; it < 8; ++it) {
            int tau = tid + it * 128;
            int row = tau >> 8;
            int px = (tau >> 3) & 31;
            int j = tau & 7;
            short8 v = *(const short8*)(tl + row * 2048 + px * 64 + ((j ^ (px & 7)) * 8));
            *(short8*)(Tp + ((size_t)b * PXP_ + (size_t)(gh0 + row + 1) * WP_ +
                             (w0 + 1 + px)) * 64 + j * 8) = v;
        }
    } else {
        // ---- epilogue: residual add from X1p (bf16, L3-hot) + f32x4 out
        const unsigned short* Xr = Xres + (size_t)b * PXP_ * 64;
        #pragma unroll
        for (int of = 0; of < 4; ++of) {
            int o = of * 16 + ln15;
            float bi = bias[b * 64 + o];
            #pragma unroll
            for (int mf = 0; mf < 4; ++mf) {
                int gh = gh0 + 2 * wv + (mf >> 1);
                int gw = w0 + 16 * (mf & 1) + g * 4;
                size_t idx = ((size_t)b * 64 + o) * HW_ + (size_t)gh * W_ + gw;
                const unsigned short* xr =
                    Xr + ((size_t)(gh + 1) * WP_ + (gw + 1)) * 64 + o;
                f32x4 ov;
                #pragma unroll
                for (int q = 0; q < 4; ++q)
                    ov[q] = bf2f(xr[(size_t)q * 64]) + acc[mf][of][q] + bi;
                *(f32x4*)(Fout + idx) = ov;
            }
        }
    }
}

extern "C" void kernel_launch(void* const* d_in, const int* in_sizes, int n_in,
                              void* d_out, int out_size, void* d_ws, size_t ws_size,
                              hipStream_t stream) {
    const float* x     = (const float*)d_in[0];
    const float* attn  = (const float*)d_in[1];
    const float* gamma = (const float*)d_in[2];
    const float* par   = (const float*)d_in[3];
    const float* w1    = (const float*)d_in[4];
    const float* b1    = (const float*)d_in[5];
    const float* w2    = (const float*)d_in[6];
    const float* b2    = (const float*)d_in[7];
    const float* w16   = (const float*)d_in[8];
    const float* w168  = (const float*)d_in[9];
    const float* w88   = (const float*)d_in[10];
    float* out = (float*)d_out;

    char* w = (char*)d_ws;
    unsigned short* W4_1 = (unsigned short*)w;                        // 786432 B
    unsigned short* W4_2 = (unsigned short*)(w + 786432);             // 589824 B
    float* bias1 = (float*)(w + 786432 + 589824);                     // 2048 B
    float* bias2 = (float*)(w + 786432 + 589824 + 2048);              // 2048 B
    unsigned short* X1p = (unsigned short*)(w + 1380352);             // 68161536 B
    unsigned short* Tp  = (unsigned short*)(w + 1380352 + 68161536);  // 68161536 B

    k_pre<<<dim3(NB_COMBINE + NB_BORDER + NB_PREP), dim3(256), 0, stream>>>(
        x, attn, gamma, w1, b1, w2, b2, w16, w168, w88,
        W4_1, W4_2, bias1, bias2, X1p, Tp);

    dim3 grid(512, 8);
    k_conv<1><<<grid, dim3(128), 0, stream>>>(X1p, nullptr, par, W4_1, bias1, Tp, nullptr);
    k_conv<2><<<grid, dim3(128), 0, stream>>>(Tp, X1p, par, W4_2, bias2, nullptr, out);
}